// Round 1
// baseline (602.373 us; speedup 1.0000x reference)
//
#include <hip/hip_runtime.h>

typedef unsigned int u32;
typedef unsigned short u16;

#define N_TOK 1024
#define D_DIM 2048
#define F_DIM 5632
#define E_NUM 8
#define R_DIM 16
#define LSCALE 2.0f

typedef __bf16 bf16x8 __attribute__((ext_vector_type(8)));
typedef float f32x4 __attribute__((ext_vector_type(4)));

__device__ inline u16 f2bf(float f) {
    u32 u = __builtin_bit_cast(u32, f);
    u32 r = (u + 0x7fffu + ((u >> 16) & 1u)) >> 16;
    return (u16)r;
}
__device__ inline float bf2f(u16 h) {
    u32 u = ((u32)h) << 16;
    return __builtin_bit_cast(float, u);
}

// ---------------- fp32 -> bf16 conversion (vectorized) ----------------
__global__ __launch_bounds__(256) void cvt_f32_bf16(const float* __restrict__ src,
                                                    u16* __restrict__ dst, int n4) {
    int i = blockIdx.x * 256 + threadIdx.x;
    if (i >= n4) return;
    float4 v = ((const float4*)src)[i];
    union { u16 h[4]; ushort4 u4; } o;
    o.h[0] = f2bf(v.x); o.h[1] = f2bf(v.y); o.h[2] = f2bf(v.z); o.h[3] = f2bf(v.w);
    ((ushort4*)dst)[i] = o.u4;
}

// ---------------- router: logits + softmax + top2 ----------------
__global__ __launch_bounds__(256) void router_kernel(const float* __restrict__ x,
                                                     const float* __restrict__ gw,
                                                     float* __restrict__ logits,
                                                     int* __restrict__ ridx,
                                                     float* __restrict__ rw) {
    int n = blockIdx.x;
    int tid = threadIdx.x;
    float part[E_NUM];
#pragma unroll
    for (int e = 0; e < E_NUM; ++e) part[e] = 0.f;
    const float* xr = x + (size_t)n * D_DIM;
    for (int d = tid; d < D_DIM; d += 256) {
        float xv = xr[d];
#pragma unroll
        for (int e = 0; e < E_NUM; ++e) part[e] += xv * gw[e * D_DIM + d];
    }
    __shared__ float sh[E_NUM][256];
#pragma unroll
    for (int e = 0; e < E_NUM; ++e) sh[e][tid] = part[e];
    __syncthreads();
    for (int off = 128; off > 0; off >>= 1) {
        if (tid < off) {
#pragma unroll
            for (int e = 0; e < E_NUM; ++e) sh[e][tid] += sh[e][tid + off];
        }
        __syncthreads();
    }
    if (tid == 0) {
        float lg[E_NUM], p[E_NUM];
        float mx = -1e30f;
        for (int e = 0; e < E_NUM; ++e) {
            lg[e] = sh[e][0];
            logits[n * E_NUM + e] = lg[e];
            if (lg[e] > mx) mx = lg[e];
        }
        float s = 0.f;
        for (int e = 0; e < E_NUM; ++e) { p[e] = expf(lg[e] - mx); s += p[e]; }
        for (int e = 0; e < E_NUM; ++e) p[e] /= s;
        int i1 = 0;
        for (int e = 1; e < E_NUM; ++e) if (p[e] > p[i1]) i1 = e;
        int i2 = (i1 == 0) ? 1 : 0;
        for (int e = 0; e < E_NUM; ++e) if (e != i1 && p[e] > p[i2]) i2 = e;
        float t = p[i1] + p[i2];
        ridx[n * 2] = i1; ridx[n * 2 + 1] = i2;
        rw[n * 2] = p[i1] / t; rw[n * 2 + 1] = p[i2] / t;
    }
}

// ---------------- bf16 MFMA GEMM, C[M,N] = A[M,K] @ B[N,K]^T ----------------
// m97 structure: 128x128 tile, BK=64, 16x16x32 MFMA, global_load_lds width 16.
__global__ __launch_bounds__(256) void gemm_bf16_bt(const u16* __restrict__ A,
                                                    const u16* __restrict__ B,
                                                    float* __restrict__ C,
                                                    int M, int N, int K, int out_bf16) {
    __shared__ __align__(16) u16 sA[128 * 64];
    __shared__ __align__(16) u16 sB[128 * 64];
    const int tid = threadIdx.x;
    const int lane = tid & 63;
    const int wave = tid >> 6;
    const int quad = lane >> 4;
    const int l16 = lane & 15;
    const int wm = (wave & 1) * 64;
    const int wn = (wave >> 1) * 64;
    const int bm0 = blockIdx.x * 128;
    const int bn0 = blockIdx.y * 128;

    f32x4 zero = {0.f, 0.f, 0.f, 0.f};
    f32x4 acc[4][4];
#pragma unroll
    for (int i = 0; i < 4; ++i)
#pragma unroll
        for (int j = 0; j < 4; ++j) acc[i][j] = zero;

    for (int k0 = 0; k0 < K; k0 += 64) {
#pragma unroll
        for (int i = 0; i < 4; ++i) {
            int c = i * 256 + tid;       // chunk id in [0,1024)
            int r = c >> 3;              // tile row
            int c8 = (c & 7) << 3;       // col (elements)
            const u16* ga = A + (size_t)(bm0 + r) * K + k0 + c8;
            const u16* gb = B + (size_t)(bn0 + r) * K + k0 + c8;
            __builtin_amdgcn_global_load_lds((const __attribute__((address_space(1))) u32*)ga,
                                             (__attribute__((address_space(3))) u32*)(sA + c * 8),
                                             16, 0, 0);
            __builtin_amdgcn_global_load_lds((const __attribute__((address_space(1))) u32*)gb,
                                             (__attribute__((address_space(3))) u32*)(sB + c * 8),
                                             16, 0, 0);
        }
        __syncthreads();
#pragma unroll
        for (int ks = 0; ks < 2; ++ks) {
            bf16x8 af[4], bfv[4];
#pragma unroll
            for (int mi = 0; mi < 4; ++mi)
                af[mi] = *(const bf16x8*)(sA + (wm + mi * 16 + l16) * 64 + ks * 32 + quad * 8);
#pragma unroll
            for (int ni = 0; ni < 4; ++ni)
                bfv[ni] = *(const bf16x8*)(sB + (wn + ni * 16 + l16) * 64 + ks * 32 + quad * 8);
#pragma unroll
            for (int mi = 0; mi < 4; ++mi)
#pragma unroll
                for (int ni = 0; ni < 4; ++ni)
                    acc[mi][ni] = __builtin_amdgcn_mfma_f32_16x16x32_bf16(af[mi], bfv[ni],
                                                                          acc[mi][ni], 0, 0, 0);
        }
        __syncthreads();
    }

#pragma unroll
    for (int mi = 0; mi < 4; ++mi)
#pragma unroll
        for (int ni = 0; ni < 4; ++ni) {
            int col = bn0 + wn + ni * 16 + l16;
#pragma unroll
            for (int i = 0; i < 4; ++i) {
                int row = bm0 + wm + mi * 16 + quad * 4 + i;
                if (out_bf16) {
                    ((u16*)C)[(size_t)row * N + col] = f2bf(acc[mi][ni][i]);
                } else {
                    C[(size_t)row * N + col] = acc[mi][ni][i];
                }
            }
        }
}

// ---------------- fused activation: LoRA-expand + SiLU*mul + mix + l2 ----------------
__global__ __launch_bounds__(256) void act_kernel(const u16* __restrict__ base1,
                                                  const u16* __restrict__ base3,
                                                  const float* __restrict__ l13,
                                                  const float* __restrict__ B1,
                                                  const float* __restrict__ B3,
                                                  const float* __restrict__ A2,
                                                  const int* __restrict__ ridx,
                                                  const float* __restrict__ rw,
                                                  u16* __restrict__ smix,
                                                  float* __restrict__ l2w) {
    int n = blockIdx.x;
    int tid = threadIdx.x;
    int lane = tid & 63;
    int wave = tid >> 6;
    __shared__ float la1[2][R_DIM], la3[2][R_DIM];
    __shared__ int se[2];
    __shared__ float sw_[2];
    __shared__ float wred[4][2][R_DIM];
    if (tid < 2) { se[tid] = ridx[n * 2 + tid]; sw_[tid] = rw[n * 2 + tid]; }
    __syncthreads();
    if (tid < 32) {
        int k = tid >> 4, r = tid & 15;
        int e = se[k];
        la1[k][r] = LSCALE * l13[(size_t)n * 256 + e * R_DIM + r];
        la3[k][r] = LSCALE * l13[(size_t)n * 256 + 128 + e * R_DIM + r];
    }
    __syncthreads();

    float a1r[2][16], a3r[2][16], l2p[2][16];
#pragma unroll
    for (int k = 0; k < 2; ++k)
#pragma unroll
        for (int r = 0; r < 16; ++r) {
            a1r[k][r] = la1[k][r];
            a3r[k][r] = la3[k][r];
            l2p[k][r] = 0.f;
        }
    int e0 = se[0], e1 = se[1];
    float w0 = sw_[0], w1 = sw_[1];
    const float* B1e[2] = { B1 + (size_t)e0 * F_DIM * R_DIM, B1 + (size_t)e1 * F_DIM * R_DIM };
    const float* B3e[2] = { B3 + (size_t)e0 * F_DIM * R_DIM, B3 + (size_t)e1 * F_DIM * R_DIM };
    const float* A2e[2] = { A2 + (size_t)e0 * R_DIM * F_DIM, A2 + (size_t)e1 * R_DIM * F_DIM };
    const u16* b1row = base1 + (size_t)n * F_DIM;
    const u16* b3row = base3 + (size_t)n * F_DIM;
    u16* srow = smix + (size_t)n * F_DIM;

    for (int j = 0; j < F_DIM / 256; ++j) {
        int f = tid + j * 256;
        float b1 = bf2f(b1row[f]);
        float b3 = bf2f(b3row[f]);
        float sval[2];
#pragma unroll
        for (int k = 0; k < 2; ++k) {
            float h1 = b1, h3 = b3;
            const float4* p1 = (const float4*)(B1e[k] + (size_t)f * 16);
            const float4* p3 = (const float4*)(B3e[k] + (size_t)f * 16);
#pragma unroll
            for (int q = 0; q < 4; ++q) {
                float4 v1 = p1[q];
                h1 += a1r[k][q * 4] * v1.x + a1r[k][q * 4 + 1] * v1.y +
                      a1r[k][q * 4 + 2] * v1.z + a1r[k][q * 4 + 3] * v1.w;
                float4 v3 = p3[q];
                h3 += a3r[k][q * 4] * v3.x + a3r[k][q * 4 + 1] * v3.y +
                      a3r[k][q * 4 + 2] * v3.z + a3r[k][q * 4 + 3] * v3.w;
            }
            float sg = h1 / (1.f + __expf(-h1));  // silu(h1)
            sval[k] = sg * h3;
        }
        srow[f] = f2bf(w0 * sval[0] + w1 * sval[1]);
#pragma unroll
        for (int k = 0; k < 2; ++k)
#pragma unroll
            for (int r = 0; r < 16; ++r)
                l2p[k][r] += sval[k] * A2e[k][(size_t)r * F_DIM + f];
    }

    // block-reduce l2p[2][16] over 256 threads
#pragma unroll
    for (int k = 0; k < 2; ++k)
#pragma unroll
        for (int r = 0; r < 16; ++r) {
            float v = l2p[k][r];
            for (int off = 32; off > 0; off >>= 1) v += __shfl_down(v, off);
            if (lane == 0) wred[wave][k][r] = v;
        }
    __syncthreads();
    if (tid < 32) {
        int k = tid >> 4;
        float v = wred[0][tid >> 4][tid & 15] + wred[1][tid >> 4][tid & 15] +
                  wred[2][tid >> 4][tid & 15] + wred[3][tid >> 4][tid & 15];
        l2w[(size_t)n * 32 + tid] = sw_[k] * LSCALE * v;
    }
}

// ---------------- LoRA down-projection add: out += l2w @ B2^T ----------------
__global__ __launch_bounds__(256) void lora_down_kernel(const float* __restrict__ l2w,
                                                        const int* __restrict__ ridx,
                                                        const float* __restrict__ B2,
                                                        float* __restrict__ out) {
    int n = blockIdx.x, tid = threadIdx.x;
    __shared__ float c0[16], c1[16];
    __shared__ int se[2];
    if (tid < 2) se[tid] = ridx[n * 2 + tid];
    if (tid < 16) c0[tid] = l2w[n * 32 + tid];
    else if (tid < 32) c1[tid - 16] = l2w[n * 32 + tid];
    __syncthreads();
    float a0[16], a1v[16];
#pragma unroll
    for (int r = 0; r < 16; ++r) { a0[r] = c0[r]; a1v[r] = c1[r]; }
    const float* B2a = B2 + (size_t)se[0] * D_DIM * R_DIM;
    const float* B2b = B2 + (size_t)se[1] * D_DIM * R_DIM;
    float* orow = out + (size_t)n * D_DIM;
    for (int d = tid; d < D_DIM; d += 256) {
        const float4* pa = (const float4*)(B2a + (size_t)d * 16);
        const float4* pb = (const float4*)(B2b + (size_t)d * 16);
        float acc = 0.f;
#pragma unroll
        for (int q = 0; q < 4; ++q) {
            float4 va = pa[q];
            acc += a0[q * 4] * va.x + a0[q * 4 + 1] * va.y +
                   a0[q * 4 + 2] * va.z + a0[q * 4 + 3] * va.w;
            float4 vb = pb[q];
            acc += a1v[q * 4] * vb.x + a1v[q * 4 + 1] * vb.y +
                   a1v[q * 4 + 2] * vb.z + a1v[q * 4 + 3] * vb.w;
        }
        orow[d] += acc;
    }
}

extern "C" void kernel_launch(void* const* d_in, const int* in_sizes, int n_in,
                              void* d_out, int out_size, void* d_ws, size_t ws_size,
                              hipStream_t stream) {
    const float* x  = (const float*)d_in[0];
    const float* gw = (const float*)d_in[1];
    const float* W1 = (const float*)d_in[2];
    const float* W3 = (const float*)d_in[3];
    const float* W2 = (const float*)d_in[4];
    const float* A1 = (const float*)d_in[5];
    const float* B1 = (const float*)d_in[6];
    const float* A3 = (const float*)d_in[7];
    const float* B3 = (const float*)d_in[8];
    const float* A2 = (const float*)d_in[9];
    const float* B2 = (const float*)d_in[10];
    float* out = (float*)d_out;                          // [N, D]
    float* logits = out + (size_t)N_TOK * D_DIM;         // [N, E]

    char* ws = (char*)d_ws;
    size_t off = 0;
    auto alloc = [&](size_t bytes) { char* p = ws + off; off += (bytes + 255) & ~(size_t)255; return p; };
    u16*   xb    = (u16*)alloc((size_t)N_TOK * D_DIM * 2);
    u16*   W1b   = (u16*)alloc((size_t)F_DIM * D_DIM * 2);
    u16*   W3b   = (u16*)alloc((size_t)F_DIM * D_DIM * 2);
    u16*   W2b   = (u16*)alloc((size_t)D_DIM * F_DIM * 2);
    u16*   A13b  = (u16*)alloc((size_t)256 * D_DIM * 2);
    u16*   base1 = (u16*)alloc((size_t)N_TOK * F_DIM * 2);
    u16*   base3 = (u16*)alloc((size_t)N_TOK * F_DIM * 2);
    float* l13   = (float*)alloc((size_t)N_TOK * 256 * 4);
    u16*   smixb = (u16*)alloc((size_t)N_TOK * F_DIM * 2);
    int*   ridx  = (int*)alloc((size_t)N_TOK * 2 * 4);
    float* rwt   = (float*)alloc((size_t)N_TOK * 2 * 4);
    float* l2w   = (float*)alloc((size_t)N_TOK * 32 * 4);
    (void)ws_size; (void)in_sizes; (void)n_in; (void)out_size;

    auto cvt = [&](const float* s, u16* d, size_t cnt) {
        int n4 = (int)(cnt / 4);
        cvt_f32_bf16<<<(n4 + 255) / 256, 256, 0, stream>>>(s, d, n4);
    };
    cvt(x,  xb,  (size_t)N_TOK * D_DIM);
    cvt(W1, W1b, (size_t)F_DIM * D_DIM);
    cvt(W3, W3b, (size_t)F_DIM * D_DIM);
    cvt(W2, W2b, (size_t)D_DIM * F_DIM);
    cvt(A1, A13b, (size_t)128 * D_DIM);
    cvt(A3, A13b + (size_t)128 * D_DIM, (size_t)128 * D_DIM);

    router_kernel<<<N_TOK, 256, 0, stream>>>(x, gw, logits, ridx, rwt);

    gemm_bf16_bt<<<dim3(N_TOK / 128, F_DIM / 128), 256, 0, stream>>>(xb, W1b, (float*)base1,
                                                                     N_TOK, F_DIM, D_DIM, 1);
    gemm_bf16_bt<<<dim3(N_TOK / 128, F_DIM / 128), 256, 0, stream>>>(xb, W3b, (float*)base3,
                                                                     N_TOK, F_DIM, D_DIM, 1);
    gemm_bf16_bt<<<dim3(N_TOK / 128, 256 / 128), 256, 0, stream>>>(xb, A13b, l13,
                                                                   N_TOK, 256, D_DIM, 0);

    act_kernel<<<N_TOK, 256, 0, stream>>>(base1, base3, l13, B1, B3, A2, ridx, rwt, smixb, l2w);

    gemm_bf16_bt<<<dim3(N_TOK / 128, D_DIM / 128), 256, 0, stream>>>(smixb, W2b, out,
                                                                     N_TOK, D_DIM, F_DIM, 0);

    lora_down_kernel<<<N_TOK, 256, 0, stream>>>(l2w, ridx, B2, out);
}